// Round 1
// 972.006 us; speedup vs baseline: 1.0361x; 1.0361x over previous
//
#include <hip/hip_runtime.h>
#include <hip/hip_bf16.h>
#include <stdint.h>

// ---------------------------------------------------------------------------
// UnitaryExpert: out = rot_theta(x @ U1^T) @ U2^T + passthrough
// U = I + 2A + 2A^2 + 2A^3 + 2A^4 + 2A^5 + A^6,  A = 0.5(W - W^T)
// Decomposition (skew A => A^T = -A, B := A^2 symmetric):
//   S1 = A*A^T = -B            (BT gemm, X=Y=A)
//   S2 = B*B^T = B^2           (BT gemm, X=Y=B)
//   F  = I + B + B^2 (symmetric)
//   S3 = A*F^T = A + A^3 + A^5 (BT gemm)
//   S4 = B^2*B^T = B^3         (BT gemm)
//   U  = I + 2*S3 - 2*S1 + 2*S2 + S4
// All matmuls use one bf16 MFMA BT-GEMM kernel (m97 recipe: 128x128 tile,
// BK=32, global_load_lds width=16, 16x16x32 MFMA).
// R1 changes vs baseline:
//  * XCD-aware bijective block swizzle (T1): the 8 bn-blocks sharing an
//    X-tile row now land on the SAME XCD L2 (was: 8 different L2s -> 4x
//    HBM over-fetch, FETCH 539MB vs 136MB compulsory on the big GEMMs).
//  * ew mode 0/1 fused into S1/S2 GEMM epilogues (bit-exact, -2 dispatches).
// ---------------------------------------------------------------------------

#define MM (1024 * 1024)

typedef __attribute__((ext_vector_type(4))) float f32x4;
typedef __attribute__((ext_vector_type(8))) short bf16x8;

__device__ __forceinline__ ushort f2bf(float f) {  // round-to-nearest-even
  uint32_t u = __builtin_bit_cast(uint32_t, f);
  u += 0x7FFFu + ((u >> 16) & 1u);
  return (ushort)(u >> 16);
}
__device__ __forceinline__ float bf2f(ushort h) {
  uint32_t u = ((uint32_t)h) << 16;
  return __builtin_bit_cast(float, u);
}

__device__ __forceinline__ void gld_lds16(const ushort* g, ushort* l) {
  // async 16B/lane global->LDS; LDS dest = wave-uniform base + lane*16
  __builtin_amdgcn_global_load_lds(
      (const __attribute__((address_space(1))) unsigned int*)g,
      (__attribute__((address_space(3))) unsigned int*)l, 16, 0, 0);
}

// ---------------------------------------------------------------------------
// BT GEMM: C[m,n] = sum_k X[m,k] * Y[n,k]   (X:[M,K], Y:[N,K], bf16 row-major)
// block = 256 threads (4 waves), tile 128x128, BK=32.
// mode 0: fp32 store to o32 + blockIdx.z*MM (z-batched small matmuls;
//         job = z>>1 selects {X0,Y0} vs {X1,Y1}, mi = z&1 selects matrix)
// mode 3: mode 0 + side output o16 = bf16(-acc)            (S1 -> Bbf)
// mode 4: mode 0 + o16 = bf16(acc), o16b = bf16(I - aux + acc)
//         (S2 -> B2bf, Fbf; aux = S1 fp32)
// mode 1: epilogue pair-rotation by theta, bf16 store to o16
// mode 2: epilogue + passthrough scalar, fp32 store to o32
// ---------------------------------------------------------------------------
__global__ __launch_bounds__(256, 2) void gemm_bt(
    const ushort* __restrict__ X0, const ushort* __restrict__ X1,
    const ushort* __restrict__ Y0, const ushort* __restrict__ Y1,
    float* __restrict__ o32, ushort* __restrict__ o16,
    ushort* __restrict__ o16b, const float* __restrict__ aux,
    int M, int N, int K, int mode,
    const float* __restrict__ theta_p, const float* __restrict__ sums) {
  __shared__ ushort lA[128 * 32];
  __shared__ ushort lB[128 * 32];

  const int tid = threadIdx.x;
  const int wave = tid >> 6, lane = tid & 63;
  const int bz = blockIdx.z;
  const int job = bz >> 1, mi = bz & 1;

  // XCD-aware bijective swizzle (8 XCDs; every launch has gridDim.x == 8 and
  // nwg % 8 == 0). HW assigns XCD = linear_id % 8; remap so XCD k owns a
  // contiguous band of bm rows -> each 128-row X tile is fetched into exactly
  // one L2 (all 8 bn-sharers co-resident on that XCD).
  const int nwg = gridDim.x * gridDim.y;
  const int lin = blockIdx.y * gridDim.x + blockIdx.x;
  const int swz = (lin & 7) * (nwg >> 3) + (lin >> 3);
  const int bn = swz & 7;   // gridDim.x == 8 always
  const int bm = swz >> 3;

  const ushort* X = (job ? X1 : X0) + (size_t)mi * MM;
  const ushort* Y = (job ? Y1 : Y0) + (size_t)mi * MM;

  // staging: thread t loads row (t>>2), k-cols (t&3)*8 .. +8 (16B)
  const ushort* Xg = X + (size_t)(bm * 128 + (tid >> 2)) * K + (tid & 3) * 8;
  const ushort* Yg = Y + (size_t)(bn * 128 + (tid >> 2)) * K + (tid & 3) * 8;
  ushort* lAw = lA + wave * 512;  // wave-uniform LDS base (1024B per wave)
  ushort* lBw = lB + wave * 512;

  const int wm = (wave & 1) * 64;   // wave's 64x64 sub-tile
  const int wn = (wave >> 1) * 64;
  const int lr = lane & 15;         // row (A) / col (B) within 16
  const int kq = (lane >> 4) * 8;   // k offset in elements

  f32x4 acc[4][4] = {};

  for (int k0 = 0; k0 < K; k0 += 32) {
    __syncthreads();
    gld_lds16(Xg + k0, lAw);
    gld_lds16(Xg + k0 + (size_t)64 * K, lAw + 64 * 32);
    gld_lds16(Yg + k0, lBw);
    gld_lds16(Yg + k0 + (size_t)64 * K, lBw + 64 * 32);
    __syncthreads();

    bf16x8 af[4], bfg[4];
#pragma unroll
    for (int t = 0; t < 4; ++t) {
      af[t] = *(const bf16x8*)(lA + (wm + t * 16 + lr) * 32 + kq);
      bfg[t] = *(const bf16x8*)(lB + (wn + t * 16 + lr) * 32 + kq);
    }
#pragma unroll
    for (int ti = 0; ti < 4; ++ti)
#pragma unroll
      for (int tj = 0; tj < 4; ++tj)
        acc[ti][tj] = __builtin_amdgcn_mfma_f32_16x16x32_bf16(
            af[ti], bfg[tj], acc[ti][tj], 0, 0, 0);
  }

  // epilogue: C/D layout col = lane&15, row = (lane>>4)*4 + reg
  const int q4 = (lane >> 4) * 4;
  if (mode == 1) {
    float th = *theta_p, s, c;
    __sincosf(th, &s, &c);
    // even col: c*x0 - s*x1 ; odd col: s*x0 + c*x1 ; partner in lane^1
    const float ssgn = (lane & 1) ? s : -s;
#pragma unroll
    for (int ti = 0; ti < 4; ++ti)
#pragma unroll
      for (int r = 0; r < 4; ++r) {
        size_t row = (size_t)(bm * 128 + wm + ti * 16 + q4 + r);
        ushort* Orow = o16 + row * N;
#pragma unroll
        for (int tj = 0; tj < 4; ++tj) {
          float v = acc[ti][tj][r];
          float w = __shfl_xor(v, 1);
          Orow[bn * 128 + wn + tj * 16 + lr] = f2bf(c * v + ssgn * w);
        }
      }
  } else if (mode == 2) {
    const float pt = 1e-6f * (sums[0] * (1.0f / 1048576.0f) +
                              sums[1] * (1.0f / 1048576.0f) + *theta_p);
#pragma unroll
    for (int ti = 0; ti < 4; ++ti)
#pragma unroll
      for (int r = 0; r < 4; ++r) {
        size_t row = (size_t)(bm * 128 + wm + ti * 16 + q4 + r);
        float* Orow = o32 + row * N;
#pragma unroll
        for (int tj = 0; tj < 4; ++tj)
          Orow[bn * 128 + wn + tj * 16 + lr] = acc[ti][tj][r] + pt;
      }
  } else {
    // modes 0/3/4: z-batched fp32 store + optional fused bf16 side outputs
    float* O = o32 + (size_t)bz * MM;
    ushort* P0 = (mode >= 3) ? o16 + (size_t)bz * MM : nullptr;
    ushort* P1 = (mode == 4) ? o16b + (size_t)bz * MM : nullptr;
    const float* Ax = (mode == 4) ? aux + (size_t)bz * MM : nullptr;
#pragma unroll
    for (int ti = 0; ti < 4; ++ti)
#pragma unroll
      for (int r = 0; r < 4; ++r) {
        const int row = bm * 128 + wm + ti * 16 + q4 + r;
        const size_t base = (size_t)row * N;
#pragma unroll
        for (int tj = 0; tj < 4; ++tj) {
          const int col = bn * 128 + wn + tj * 16 + lr;
          const float v = acc[ti][tj][r];
          O[base + col] = v;
          if (mode == 3) {
            P0[base + col] = f2bf(-v);
          } else if (mode == 4) {
            P0[base + col] = f2bf(v);
            const float diag = (row == col) ? 1.f : 0.f;
            P1[base + col] = f2bf(diag - Ax[base + col] + v);
          }
        }
      }
  }
}

// ---------------------------------------------------------------------------
// A = 0.5(W - W^T) -> bf16, fused sum(W) reduction (for passthrough mean).
// grid (32,32,2), block (32,8); 32x32 tile, transpose via LDS.
// ---------------------------------------------------------------------------
__global__ __launch_bounds__(256) void prep_a(const float* __restrict__ W1,
                                              const float* __restrict__ W2,
                                              ushort* __restrict__ Abf,
                                              float* __restrict__ sums) {
  __shared__ float sT[32][33];
  const int z = blockIdx.z;
  const float* W = z ? W2 : W1;
  ushort* A = Abf + (size_t)z * MM;
  const int r0 = blockIdx.y * 32, c0 = blockIdx.x * 32;
  const int x = threadIdx.x, y = threadIdx.y;

#pragma unroll
  for (int k = 0; k < 4; ++k)
    sT[y + 8 * k][x] = W[(size_t)(c0 + y + 8 * k) * 1024 + r0 + x];
  __syncthreads();

  float lsum = 0.f;
#pragma unroll
  for (int k = 0; k < 4; ++k) {
    int i = y + 8 * k;
    float w = W[(size_t)(r0 + i) * 1024 + c0 + x];
    lsum += w;
    A[(size_t)(r0 + i) * 1024 + c0 + x] = f2bf(0.5f * (w - sT[x][i]));
  }
#pragma unroll
  for (int off = 32; off > 0; off >>= 1) lsum += __shfl_down(lsum, off);
  if (((y * 32 + x) & 63) == 0) atomicAdd(&sums[z], lsum);
}

// x fp32 -> bf16, vectorized (float4 per thread)
__global__ __launch_bounds__(256) void cvt_x(const float* __restrict__ x,
                                             ushort* __restrict__ xb) {
  const size_t i = (size_t)blockIdx.x * 256 + threadIdx.x;
  float4 v = ((const float4*)x)[i];
  ushort4 o;
  o.x = f2bf(v.x);
  o.y = f2bf(v.y);
  o.z = f2bf(v.z);
  o.w = f2bf(v.w);
  ((ushort4*)xb)[i] = o;
}

// final elementwise combine over 2*MM elements (two matrices):
//   Ubf = bf16(I - 2*S1 + 2*S2 + 2*S3 + S4)
__global__ __launch_bounds__(256) void ew(const float* __restrict__ S1,
                                          const float* __restrict__ S2,
                                          const float* __restrict__ S3,
                                          const float* __restrict__ S4,
                                          ushort* __restrict__ O0) {
  const int idx = blockIdx.x * 256 + threadIdx.x;  // exactly 2*MM threads
  const int local = idx & (MM - 1);
  const float diag = ((local >> 10) == (local & 1023)) ? 1.f : 0.f;
  O0[idx] =
      f2bf(diag - 2.f * S1[idx] + 2.f * S2[idx] + 2.f * S3[idx] + S4[idx]);
}

extern "C" void kernel_launch(void* const* d_in, const int* in_sizes, int n_in,
                              void* d_out, int out_size, void* d_ws,
                              size_t ws_size, hipStream_t stream) {
  const float* xin = (const float*)d_in[0];
  const float* w1 = (const float*)d_in[1];
  const float* w2 = (const float*)d_in[2];
  const float* th = (const float*)d_in[3];
  float* out = (float*)d_out;

  // workspace carve (all 256B-aligned)
  char* w = (char*)d_ws;
  float* sums = (float*)w;                       // 8 B
  ushort* Abf = (ushort*)(w + 256);              // 2*MM bf16 = 4 MB
  ushort* Bbf = Abf + 2 * MM;                    // 4 MB
  ushort* B2bf = Bbf + 2 * MM;                   // 4 MB
  ushort* Fbf = B2bf + 2 * MM;                   // 4 MB
  ushort* Ubf = Fbf + 2 * MM;                    // 4 MB (U1, U2)
  float* S1 = (float*)(Ubf + 2 * MM);            // 8 MB
  float* S2 = S1 + 2 * MM;                       // 8 MB
  float* S34 = S2 + 2 * MM;                      // 16 MB (S3: z0,1 / S4: z2,3)
  ushort* xbf = (ushort*)(S34 + 4 * MM);         // 128 MB
  ushort* hbf = xbf + (size_t)65536 * 1024;      // 128 MB

  hipMemsetAsync(sums, 0, 2 * sizeof(float), stream);

  prep_a<<<dim3(32, 32, 2), dim3(32, 8), 0, stream>>>(w1, w2, Abf, sums);
  cvt_x<<<65536, 256, 0, stream>>>(xin, xbf);

  // S1 = A*A^T ; fused: Bbf = bf16(-S1)
  gemm_bt<<<dim3(8, 8, 2), 256, 0, stream>>>(Abf, Abf, Abf, Abf, S1, Bbf,
                                             nullptr, nullptr, 1024, 1024,
                                             1024, 3, th, sums);
  // S2 = B*B^T = B^2 ; fused: B2bf = bf16(S2), Fbf = bf16(I - S1 + S2)
  gemm_bt<<<dim3(8, 8, 2), 256, 0, stream>>>(Bbf, Bbf, Bbf, Bbf, S2, B2bf,
                                             Fbf, S1, 1024, 1024, 1024, 4, th,
                                             sums);
  // S3 = A*F^T (z0,1) ; S4 = B2*B^T (z2,3)
  gemm_bt<<<dim3(8, 8, 4), 256, 0, stream>>>(Abf, B2bf, Fbf, Bbf, S34, nullptr,
                                             nullptr, nullptr, 1024, 1024,
                                             1024, 0, th, sums);
  ew<<<8192, 256, 0, stream>>>(S1, S2, S34, S34 + 2 * MM, Ubf);

  // h = rot_theta(x @ U1^T)  -> bf16
  gemm_bt<<<dim3(8, 512, 1), 256, 0, stream>>>(xbf, xbf, Ubf, Ubf, nullptr,
                                               hbf, nullptr, nullptr, 65536,
                                               1024, 1024, 1, th, sums);
  // out = h @ U2^T + passthrough -> fp32
  gemm_bt<<<dim3(8, 512, 1), 256, 0, stream>>>(hbf, hbf, Ubf + MM, Ubf + MM,
                                               out, nullptr, nullptr, nullptr,
                                               65536, 1024, 1024, 2, th, sums);
}

// Round 2
// 913.616 us; speedup vs baseline: 1.1023x; 1.0639x over previous
//
#include <hip/hip_runtime.h>
#include <hip/hip_bf16.h>
#include <stdint.h>

// ---------------------------------------------------------------------------
// UnitaryExpert: out = rot_theta(x @ U1^T) @ U2^T + passthrough
// U = I + 2A + 2A^2 + 2A^3 + 2A^4 + 2A^5 + A^6,  A = 0.5(W - W^T)
// Decomposition (skew A => A^T = -A, B := A^2 symmetric):
//   S1 = A*A^T = -B ; S2 = B*B^T = B^2 ; F = I + B + B^2
//   S3 = A*F^T ; S4 = B^2*B^T ; U = I + 2*S3 - 2*S1 + 2*S2 + S4
// R2: big GEMMs (65536x1024x1024) moved to a 256x256-tile 8-wave 4-phase/K-tile
// kernel (T2 LDS XOR-swizzle + T3/T4 counted vmcnt + T5 setprio + T1 XCD
// swizzle). Small 1024^3 chain stays on the m97-style kernel (gemm_bt).
// ---------------------------------------------------------------------------

#define MM (1024 * 1024)

typedef __attribute__((ext_vector_type(4))) float f32x4;
typedef __attribute__((ext_vector_type(8))) short bf16x8;

__device__ __forceinline__ ushort f2bf(float f) {  // round-to-nearest-even
  uint32_t u = __builtin_bit_cast(uint32_t, f);
  u += 0x7FFFu + ((u >> 16) & 1u);
  return (ushort)(u >> 16);
}

__device__ __forceinline__ void gld_lds16(const ushort* g, ushort* l) {
  // async 16B/lane global->LDS; LDS dest = wave-uniform base + lane*16
  __builtin_amdgcn_global_load_lds(
      (const __attribute__((address_space(1))) unsigned int*)g,
      (__attribute__((address_space(3))) unsigned int*)l, 16, 0, 0);
}

// ===========================================================================
// gemm256: C[m,n] = sum_k X[m,k]*Y[n,k], X:[M,K], Y:[N,K] bf16 row-major.
// BM=BN=256, BK=64, 512 thr (8 waves, 2M x 4N), per-wave out 128x64.
// LDS 128 KiB: 2 bufs x (A[256][64] | B[256][64]) bf16, XOR-swizzled
// (byte ^= (row&7)<<4) via pre-swizzled global source + swizzled ds_read.
// Schedule per K-tile: 4 phases (C-quadrants), 1 half-tile staged per phase
// into buf[nxt], single counted vmcnt(2) per K-tile (never 0 mid-loop).
// mode 1: pair-rotation epilogue -> bf16 o16 ; mode 2: +passthrough -> f32 o32
// Requires: N==1024 (grid.x==4), M%256==0, K%64==0.
// ===========================================================================
#define STAGE(GS, LB, BUF, H, KT)                                    \
  do {                                                               \
    const ushort* g_ = (GS) + (size_t)((H)*128) * K + (size_t)(KT)*64; \
    ushort* d_ = (LB) + (BUF)*32768 + (H)*128 * 64;                  \
    gld_lds16(g_, d_);                                               \
    gld_lds16(g_ + (size_t)64 * K, d_ + 64 * 64);                    \
  } while (0)

#define LDA(MH, BUF)                                                    \
  do {                                                                  \
    _Pragma("unroll") for (int ti = 0; ti < 4; ++ti) {                  \
      const ushort* p_ = rdA + (BUF)*32768 + ((MH)*64 + ti * 16 + lr) * 64; \
      af[ti][0] = *(const bf16x8*)(p_ + (pcol0 >> 1));                  \
      af[ti][1] = *(const bf16x8*)(p_ + (pcol1 >> 1));                  \
    }                                                                   \
  } while (0)

#define LDB(NH, BUF)                                                    \
  do {                                                                  \
    _Pragma("unroll") for (int tj = 0; tj < 2; ++tj) {                  \
      const ushort* p_ = rdB + (BUF)*32768 + ((NH)*32 + tj * 16 + lr) * 64; \
      bfr[tj][0] = *(const bf16x8*)(p_ + (pcol0 >> 1));                 \
      bfr[tj][1] = *(const bf16x8*)(p_ + (pcol1 >> 1));                 \
    }                                                                   \
  } while (0)

#define MFMA16(MH, NH)                                                  \
  do {                                                                  \
    __builtin_amdgcn_s_setprio(1);                                      \
    _Pragma("unroll") for (int m_ = 0; m_ < 4; ++m_)                    \
    _Pragma("unroll") for (int n_ = 0; n_ < 2; ++n_)                    \
    _Pragma("unroll") for (int ks_ = 0; ks_ < 2; ++ks_)                 \
      acc[(MH)*4 + m_][(NH)*2 + n_] =                                   \
          __builtin_amdgcn_mfma_f32_16x16x32_bf16(                      \
              af[m_][ks_], bfr[n_][ks_], acc[(MH)*4 + m_][(NH)*2 + n_], \
              0, 0, 0);                                                 \
    __builtin_amdgcn_s_setprio(0);                                      \
  } while (0)

#define CFENCE asm volatile("" ::: "memory")
#define SBAR                                  \
  do {                                        \
    CFENCE;                                   \
    __builtin_amdgcn_s_barrier();             \
    __builtin_amdgcn_sched_barrier(0);        \
  } while (0)

__global__ __launch_bounds__(512, 2) void gemm256(
    const ushort* __restrict__ X, const ushort* __restrict__ Y,
    float* __restrict__ o32, ushort* __restrict__ o16, int M, int N, int K,
    int mode, const float* __restrict__ theta_p,
    const float* __restrict__ sums) {
  extern __shared__ ushort lds[];  // [buf][A:16384 | B:16384] ushorts

  const int tid = threadIdx.x;
  const int wave = tid >> 6, lane = tid & 63;

  // T1: XCD-chunked bijective swizzle (nwg = 1024, multiple of 8)
  const int nwg = gridDim.x * gridDim.y;
  const int lin = blockIdx.y * gridDim.x + blockIdx.x;
  const int wgid = (lin & 7) * (nwg >> 3) + (lin >> 3);
  const int bn = wgid & 3;   // gridDim.x == 4 (N = 1024)
  const int bm = wgid >> 2;

  const int wrow = wave >> 2;  // 0..1
  const int wcol = wave & 3;   // 0..3

  // staging: thread covers row srow (of 64-row slab), 16B at swizzled k-col
  const int srow = wave * 8 + (lane >> 3);
  const int scol = (((lane & 7) ^ ((lane >> 3) & 7)) << 3);  // elems
  const ushort* Xs = X + (size_t)(bm * 256 + srow) * K + scol;
  const ushort* Ys = Y + (size_t)(bn * 256 + srow) * K + scol;
  ushort* stA = lds + wave * 8 * 64;           // + buf*32768 + h*128*64
  ushort* stB = lds + 16384 + wave * 8 * 64;

  // reads: row-local XOR swizzle; (row&7) == (lr&7) since bases are %8==0
  const int lr = lane & 15;
  const int kqb = (lane >> 4) << 4;       // byte 0/16/32/48
  const int swz = (lr & 7) << 4;
  const int pcol0 = (0 + kqb) ^ swz;      // bytes, k-slice 0
  const int pcol1 = (64 + kqb) ^ swz;     // bytes, k-slice 1
  const ushort* rdA = lds + wrow * 128 * 64;
  const ushort* rdB = lds + 16384 + wcol * 64 * 64;

  f32x4 acc[8][4] = {};
  bf16x8 af[4][2], bfr[2][2];

  const int NT = K >> 6;

  // prologue: stage tile 0 -> buf0 (8 loads/wave)
  STAGE(Xs, stA, 0, 0, 0);
  STAGE(Xs, stA, 0, 1, 0);
  STAGE(Ys, stB, 0, 0, 0);
  STAGE(Ys, stB, 0, 1, 0);

  for (int t = 0; t < NT; ++t) {
    const int cur = t & 1, nxt = cur ^ 1;
    const bool pf = (t + 1 < NT);
    // -- phase 1: quadrant (0,0); stage A-h0(t+1); residency gate for tile t
    if (pf) {
      STAGE(Xs, stA, nxt, 0, t + 1);
      asm volatile("s_waitcnt vmcnt(2)" ::: "memory");
    } else {
      asm volatile("s_waitcnt vmcnt(0)" ::: "memory");
    }
    SBAR;
    LDA(0, cur);
    LDB(0, cur);
    MFMA16(0, 0);
    SBAR;
    // -- phase 2: (0,1); stage A-h1(t+1)
    LDB(1, cur);
    if (pf) STAGE(Xs, stA, nxt, 1, t + 1);
    SBAR;
    MFMA16(0, 1);
    SBAR;
    // -- phase 3: (1,1); stage B-h0(t+1)
    LDA(1, cur);
    if (pf) STAGE(Ys, stB, nxt, 0, t + 1);
    SBAR;
    MFMA16(1, 1);
    SBAR;
    // -- phase 4: (1,0); stage B-h1(t+1)
    LDB(0, cur);
    if (pf) STAGE(Ys, stB, nxt, 1, t + 1);
    SBAR;
    MFMA16(1, 0);
    SBAR;
  }

  // epilogue: C/D layout col = lane&15, row = (lane>>4)*4 + reg
  const int q4 = (lane >> 4) * 4;
  const int rbase = bm * 256 + wrow * 128;
  const int cbase = bn * 256 + wcol * 64;
  if (mode == 1) {
    float th = *theta_p, s, c;
    __sincosf(th, &s, &c);
    const float ssgn = (lane & 1) ? s : -s;
#pragma unroll
    for (int fi = 0; fi < 8; ++fi)
#pragma unroll
      for (int r = 0; r < 4; ++r) {
        const size_t row = (size_t)(rbase + fi * 16 + q4 + r);
        ushort* Orow = o16 + row * N;
#pragma unroll
        for (int fj = 0; fj < 4; ++fj) {
          float v = acc[fi][fj][r];
          float w = __shfl_xor(v, 1);
          Orow[cbase + fj * 16 + lr] = f2bf(c * v + ssgn * w);
        }
      }
  } else {
    const float pt = 1e-6f * (sums[0] * (1.0f / 1048576.0f) +
                              sums[1] * (1.0f / 1048576.0f) + *theta_p);
#pragma unroll
    for (int fi = 0; fi < 8; ++fi)
#pragma unroll
      for (int r = 0; r < 4; ++r) {
        const size_t row = (size_t)(rbase + fi * 16 + q4 + r);
        float* Orow = o32 + row * N;
#pragma unroll
        for (int fj = 0; fj < 4; ++fj)
          Orow[cbase + fj * 16 + lr] = acc[fi][fj][r] + pt;
      }
  }
}

// ---------------------------------------------------------------------------
// BT GEMM (m97 structure) for the small 1024^3 chain.
// mode 0: fp32 -> o32 + z*MM ; mode 3: +o16 = bf16(-acc)
// mode 4: +o16 = bf16(acc), o16b = bf16(I - aux + acc)
// ---------------------------------------------------------------------------
__global__ __launch_bounds__(256, 2) void gemm_bt(
    const ushort* __restrict__ X0, const ushort* __restrict__ X1,
    const ushort* __restrict__ Y0, const ushort* __restrict__ Y1,
    float* __restrict__ o32, ushort* __restrict__ o16,
    ushort* __restrict__ o16b, const float* __restrict__ aux, int M, int N,
    int K, int mode, const float* __restrict__ theta_p,
    const float* __restrict__ sums) {
  __shared__ ushort lA[128 * 32];
  __shared__ ushort lB[128 * 32];

  const int tid = threadIdx.x;
  const int wave = tid >> 6, lane = tid & 63;
  const int bz = blockIdx.z;
  const int job = bz >> 1, mi = bz & 1;

  const int nwg = gridDim.x * gridDim.y;
  const int lin = blockIdx.y * gridDim.x + blockIdx.x;
  const int swzb = (lin & 7) * (nwg >> 3) + (lin >> 3);
  const int bn = swzb & 7;  // gridDim.x == 8 always
  const int bm = swzb >> 3;

  const ushort* X = (job ? X1 : X0) + (size_t)mi * MM;
  const ushort* Y = (job ? Y1 : Y0) + (size_t)mi * MM;

  const ushort* Xg = X + (size_t)(bm * 128 + (tid >> 2)) * K + (tid & 3) * 8;
  const ushort* Yg = Y + (size_t)(bn * 128 + (tid >> 2)) * K + (tid & 3) * 8;
  ushort* lAw = lA + wave * 512;
  ushort* lBw = lB + wave * 512;

  const int wm = (wave & 1) * 64;
  const int wn = (wave >> 1) * 64;
  const int lr = lane & 15;
  const int kq = (lane >> 4) * 8;

  f32x4 acc[4][4] = {};

  for (int k0 = 0; k0 < K; k0 += 32) {
    __syncthreads();
    gld_lds16(Xg + k0, lAw);
    gld_lds16(Xg + k0 + (size_t)64 * K, lAw + 64 * 32);
    gld_lds16(Yg + k0, lBw);
    gld_lds16(Yg + k0 + (size_t)64 * K, lBw + 64 * 32);
    __syncthreads();

    bf16x8 afv[4], bfg[4];
#pragma unroll
    for (int t = 0; t < 4; ++t) {
      afv[t] = *(const bf16x8*)(lA + (wm + t * 16 + lr) * 32 + kq);
      bfg[t] = *(const bf16x8*)(lB + (wn + t * 16 + lr) * 32 + kq);
    }
#pragma unroll
    for (int ti = 0; ti < 4; ++ti)
#pragma unroll
      for (int tj = 0; tj < 4; ++tj)
        acc[ti][tj] = __builtin_amdgcn_mfma_f32_16x16x32_bf16(
            afv[ti], bfg[tj], acc[ti][tj], 0, 0, 0);
  }

  const int q4 = (lane >> 4) * 4;
  float* O = o32 + (size_t)bz * MM;
  ushort* P0 = (mode >= 3) ? o16 + (size_t)bz * MM : nullptr;
  ushort* P1 = (mode == 4) ? o16b + (size_t)bz * MM : nullptr;
  const float* Ax = (mode == 4) ? aux + (size_t)bz * MM : nullptr;
#pragma unroll
  for (int ti = 0; ti < 4; ++ti)
#pragma unroll
    for (int r = 0; r < 4; ++r) {
      const int row = bm * 128 + wm + ti * 16 + q4 + r;
      const size_t base = (size_t)row * N;
#pragma unroll
      for (int tj = 0; tj < 4; ++tj) {
        const int col = bn * 128 + wn + tj * 16 + lr;
        const float v = acc[ti][tj][r];
        O[base + col] = v;
        if (mode == 3) {
          P0[base + col] = f2bf(-v);
        } else if (mode == 4) {
          P0[base + col] = f2bf(v);
          const float diag = (row == col) ? 1.f : 0.f;
          P1[base + col] = f2bf(diag - Ax[base + col] + v);
        }
      }
    }
}

// ---------------------------------------------------------------------------
// A = 0.5(W - W^T) -> bf16, fused sum(W) reduction (for passthrough mean).
// ---------------------------------------------------------------------------
__global__ __launch_bounds__(256) void prep_a(const float* __restrict__ W1,
                                              const float* __restrict__ W2,
                                              ushort* __restrict__ Abf,
                                              float* __restrict__ sums) {
  __shared__ float sT[32][33];
  const int z = blockIdx.z;
  const float* W = z ? W2 : W1;
  ushort* A = Abf + (size_t)z * MM;
  const int r0 = blockIdx.y * 32, c0 = blockIdx.x * 32;
  const int x = threadIdx.x, y = threadIdx.y;

#pragma unroll
  for (int k = 0; k < 4; ++k)
    sT[y + 8 * k][x] = W[(size_t)(c0 + y + 8 * k) * 1024 + r0 + x];
  __syncthreads();

  float lsum = 0.f;
#pragma unroll
  for (int k = 0; k < 4; ++k) {
    int i = y + 8 * k;
    float w = W[(size_t)(r0 + i) * 1024 + c0 + x];
    lsum += w;
    A[(size_t)(r0 + i) * 1024 + c0 + x] = f2bf(0.5f * (w - sT[x][i]));
  }
#pragma unroll
  for (int off = 32; off > 0; off >>= 1) lsum += __shfl_down(lsum, off);
  if (((y * 32 + x) & 63) == 0) atomicAdd(&sums[z], lsum);
}

// x fp32 -> bf16, vectorized (float4 per thread)
__global__ __launch_bounds__(256) void cvt_x(const float* __restrict__ x,
                                             ushort* __restrict__ xb) {
  const size_t i = (size_t)blockIdx.x * 256 + threadIdx.x;
  float4 v = ((const float4*)x)[i];
  ushort4 o;
  o.x = f2bf(v.x);
  o.y = f2bf(v.y);
  o.z = f2bf(v.z);
  o.w = f2bf(v.w);
  ((ushort4*)xb)[i] = o;
}

// Ubf = bf16(I - 2*S1 + 2*S2 + 2*S3 + S4) over 2*MM elements
__global__ __launch_bounds__(256) void ew(const float* __restrict__ S1,
                                          const float* __restrict__ S2,
                                          const float* __restrict__ S3,
                                          const float* __restrict__ S4,
                                          ushort* __restrict__ O0) {
  const int idx = blockIdx.x * 256 + threadIdx.x;  // exactly 2*MM threads
  const int local = idx & (MM - 1);
  const float diag = ((local >> 10) == (local & 1023)) ? 1.f : 0.f;
  O0[idx] =
      f2bf(diag - 2.f * S1[idx] + 2.f * S2[idx] + 2.f * S3[idx] + S4[idx]);
}

extern "C" void kernel_launch(void* const* d_in, const int* in_sizes, int n_in,
                              void* d_out, int out_size, void* d_ws,
                              size_t ws_size, hipStream_t stream) {
  const float* xin = (const float*)d_in[0];
  const float* w1 = (const float*)d_in[1];
  const float* w2 = (const float*)d_in[2];
  const float* th = (const float*)d_in[3];
  float* out = (float*)d_out;

  // workspace carve (all 256B-aligned)
  char* w = (char*)d_ws;
  float* sums = (float*)w;                    // 8 B
  ushort* Abf = (ushort*)(w + 256);           // 4 MB
  ushort* Bbf = Abf + 2 * MM;                 // 4 MB
  ushort* B2bf = Bbf + 2 * MM;                // 4 MB
  ushort* Fbf = B2bf + 2 * MM;                // 4 MB
  ushort* Ubf = Fbf + 2 * MM;                 // 4 MB (U1, U2)
  float* S1 = (float*)(Ubf + 2 * MM);         // 8 MB
  float* S2 = S1 + 2 * MM;                    // 8 MB
  float* S34 = S2 + 2 * MM;                   // 16 MB (S3: z0,1 / S4: z2,3)
  ushort* xbf = (ushort*)(S34 + 4 * MM);      // 128 MB
  ushort* hbf = xbf + (size_t)65536 * 1024;   // 128 MB

  static bool inited = false;
  if (!inited) {
    (void)hipFuncSetAttribute((const void*)gemm256,
                              hipFuncAttributeMaxDynamicSharedMemorySize,
                              131072);
    inited = true;
  }

  hipMemsetAsync(sums, 0, 2 * sizeof(float), stream);

  prep_a<<<dim3(32, 32, 2), dim3(32, 8), 0, stream>>>(w1, w2, Abf, sums);
  cvt_x<<<65536, 256, 0, stream>>>(xin, xbf);

  // S1 = A*A^T ; fused: Bbf = bf16(-S1)
  gemm_bt<<<dim3(8, 8, 2), 256, 0, stream>>>(Abf, Abf, Abf, Abf, S1, Bbf,
                                             nullptr, nullptr, 1024, 1024,
                                             1024, 3, th, sums);
  // S2 = B^2 ; fused: B2bf = bf16(S2), Fbf = bf16(I - S1 + S2)
  gemm_bt<<<dim3(8, 8, 2), 256, 0, stream>>>(Bbf, Bbf, Bbf, Bbf, S2, B2bf, Fbf,
                                             S1, 1024, 1024, 1024, 4, th,
                                             sums);
  // S3 = A*F^T (z0,1) ; S4 = B2*B^T (z2,3)
  gemm_bt<<<dim3(8, 8, 4), 256, 0, stream>>>(Abf, B2bf, Fbf, Bbf, S34, nullptr,
                                             nullptr, nullptr, 1024, 1024,
                                             1024, 0, th, sums);
  ew<<<8192, 256, 0, stream>>>(S1, S2, S34, S34 + 2 * MM, Ubf);

  // h = rot_theta(x @ U1^T) -> bf16   (256^2-tile 8-phase kernel)
  gemm256<<<dim3(4, 256, 1), 512, 131072, stream>>>(
      xbf, Ubf, nullptr, hbf, 65536, 1024, 1024, 1, th, sums);
  // out = h @ U2^T + passthrough -> fp32
  gemm256<<<dim3(4, 256, 1), 512, 131072, stream>>>(
      hbf, Ubf + MM, out, nullptr, 65536, 1024, 1024, 2, th, sums);
}